// Round 6
// baseline (1286.599 us; speedup 1.0000x reference)
//
#include <hip/hip_runtime.h>
#include <hip/hip_bf16.h>
#include <math.h>

// ---------------------------------------------------------------------------
// B=1024, D_DATA=16384, D_LAT=256, N_GRID=256. Inputs f32.
// OUTPUT (decoded R0-R5): d_out is a float32 array, one f32 per output
// (total, recon, kl, topo). Harness reads the HIGH uint16 of each f32 slot
// (u<<16 -> bf16). We store (float)__float2bfloat16(v) so the high half is
// the exact RNE bf16 of v.
//
// ws layout (floats):
//   [0..2047]    recon partials   [2048..4095] kl partials
//   [4096]       topo             [4104..5127] sq (1024)
//   [8192..]     dist 1024x1024 (4 MB)
// ---------------------------------------------------------------------------

#define NBLK 2048

__global__ __launch_bounds__(256) void losses_kernel(const float4* __restrict__ rx,
                                                     const float4* __restrict__ x,
                                                     const float4* __restrict__ mu,
                                                     const float4* __restrict__ lv,
                                                     const float* __restrict__ z,
                                                     float* __restrict__ partials,
                                                     float* __restrict__ sq) {
  const int t = threadIdx.x;
  const int gid = blockIdx.x * 256 + t;
  const int gstride = NBLK * 256;

  float rs = 0.f;
  for (int i = gid; i < 4194304; i += gstride) {
    float4 a = rx[i], b = x[i];
    float dx = a.x - b.x, dy = a.y - b.y, dz = a.z - b.z, dw = a.w - b.w;
    rs += dx * dx + dy * dy + dz * dz + dw * dw;
  }
  float ks = 0.f;
  for (int i = gid; i < 65536; i += gstride) {
    float4 m = mu[i], l = lv[i];
    ks += 1.f + l.x - m.x * m.x - __expf(l.x);
    ks += 1.f + l.y - m.y * m.y - __expf(l.y);
    ks += 1.f + l.z - m.z * m.z - __expf(l.z);
    ks += 1.f + l.w - m.w * m.w - __expf(l.w);
  }
#pragma unroll
  for (int off = 32; off; off >>= 1) {
    rs += __shfl_xor(rs, off);
    ks += __shfl_xor(ks, off);
  }
  __shared__ float red[8];
  if ((t & 63) == 0) { red[t >> 6] = rs; red[4 + (t >> 6)] = ks; }
  __syncthreads();
  if (t == 0) {
    partials[blockIdx.x] = red[0] + red[1] + red[2] + red[3];
    partials[NBLK + blockIdx.x] = red[4] + red[5] + red[6] + red[7];
  }
  if (blockIdx.x < 256) {
    const int lane = t & 63;
    const int row = blockIdx.x * 4 + (t >> 6);
    float4 v = ((const float4*)(z + row * 256))[lane];
    float s = v.x * v.x + v.y * v.y + v.z * v.z + v.w * v.w;
#pragma unroll
    for (int off = 32; off; off >>= 1) s += __shfl_xor(s, off);
    if (lane == 0) sq[row] = s;
  }
}

__global__ __launch_bounds__(256) void dist_kernel(const float* __restrict__ z,
                                                   const float* __restrict__ sq,
                                                   float* __restrict__ dist) {
  __shared__ float A[64][68];
  __shared__ float Bs[64][68];
  const int i0 = blockIdx.y * 64, j0 = blockIdx.x * 64;
  const int t = threadIdx.x;
  const int tx = t & 15;
  const int ty = t >> 4;
  float acc[4][4] = {};
  for (int k0 = 0; k0 < 256; k0 += 64) {
    __syncthreads();
#pragma unroll
    for (int it = 0; it < 4; ++it) {
      int lin = it * 256 + t;
      int row = lin >> 4, q = lin & 15;
      *(float4*)&A[row][q * 4]  = *(const float4*)(z + (i0 + row) * 256 + k0 + q * 4);
      *(float4*)&Bs[row][q * 4] = *(const float4*)(z + (j0 + row) * 256 + k0 + q * 4);
    }
    __syncthreads();
#pragma unroll 4
    for (int k = 0; k < 64; k += 4) {
      float4 av[4], bv[4];
#pragma unroll
      for (int rr = 0; rr < 4; ++rr) av[rr] = *(const float4*)&A[ty + 16 * rr][k];
#pragma unroll
      for (int cc = 0; cc < 4; ++cc) bv[cc] = *(const float4*)&Bs[tx + 16 * cc][k];
#pragma unroll
      for (int rr = 0; rr < 4; ++rr)
#pragma unroll
        for (int cc = 0; cc < 4; ++cc) {
          acc[rr][cc] += av[rr].x * bv[cc].x;
          acc[rr][cc] += av[rr].y * bv[cc].y;
          acc[rr][cc] += av[rr].z * bv[cc].z;
          acc[rr][cc] += av[rr].w * bv[cc].w;
        }
    }
  }
#pragma unroll
  for (int rr = 0; rr < 4; ++rr) {
    int i = i0 + ty + 16 * rr;
    float sqi = sq[i];
#pragma unroll
    for (int cc = 0; cc < 4; ++cc) {
      int j = j0 + tx + 16 * cc;
      float d2 = sqi + sq[j] - 2.f * acc[rr][cc];
      dist[i * 1024 + j] = sqrtf(fmaxf(d2, 0.f) + 1e-12f);
    }
  }
}

__global__ __launch_bounds__(256) void prim_sil_kernel(const float* __restrict__ dist,
                                                       float* __restrict__ topo_out) {
  __shared__ float dsh[1023];
  __shared__ float red[8];
  __shared__ float red2[4];
  const int t = threadIdx.x;

  if (t < 64) {
    const int lane = t;
    float md[16];
#pragma unroll
    for (int r = 0; r < 16; ++r) md[r] = dist[r * 64 + lane];
    unsigned mask = (lane == 0) ? 1u : 0u;
    for (int step = 0; step < 1023; ++step) {
      float bv = (mask & 1u) ? INFINITY : md[0];
      int bi = lane;
#pragma unroll
      for (int r = 1; r < 16; ++r) {
        float c = ((mask >> r) & 1u) ? INFINITY : md[r];
        if (c < bv) { bv = c; bi = r * 64 + lane; }
      }
#pragma unroll
      for (int off = 32; off; off >>= 1) {
        float ov = __shfl_xor(bv, off);
        int oi = __shfl_xor(bi, off);
        if (ov < bv || (ov == bv && oi < bi)) { bv = ov; bi = oi; }
      }
      if (lane == 0) dsh[step] = bv;
      if ((bi & 63) == lane) mask |= 1u << (bi >> 6);
      const float* row = dist + bi * 1024;
#pragma unroll
      for (int r = 0; r < 16; ++r) md[r] = fminf(md[r], row[r * 64 + lane]);
    }
  }
  __syncthreads();

  float lmax = 0.f, lsum = 0.f;
  for (int i = t; i < 1023; i += 256) {
    float v = dsh[i];
    lmax = fmaxf(lmax, v);
    lsum += v;
  }
#pragma unroll
  for (int off = 32; off; off >>= 1) {
    lmax = fmaxf(lmax, __shfl_xor(lmax, off));
    lsum += __shfl_xor(lsum, off);
  }
  if ((t & 63) == 0) { red[t >> 6] = lmax; red[4 + (t >> 6)] = lsum; }
  __syncthreads();
  float tmax = fmaxf(fmaxf(red[0], red[1]), fmaxf(red[2], red[3]));
  float wsum = red[4] + red[5] + red[6] + red[7];
  float tt = (float)t * (1.0f / 255.0f) * tmax;
  float acc = 0.f;
  for (int j = 0; j < 1023; ++j) {
    float dj = dsh[j];
    acc += dj * fmaxf(fminf(tt, dj - tt), 0.f);
  }
  float phi = acc / (wsum + 1e-12f);
#pragma unroll
  for (int off = 32; off; off >>= 1) phi += __shfl_xor(phi, off);
  if ((t & 63) == 0) red2[t >> 6] = phi;
  __syncthreads();
  if (t == 0) topo_out[0] = (red2[0] + red2[1] + red2[2] + red2[3]) * (1.f / 256.f);
}

// final: sum partials, combine; d_out = float32 slots, value pre-rounded bf16
__global__ __launch_bounds__(256) void final_kernel(const float* __restrict__ ws,
                                                    float* __restrict__ out) {
  const int t = threadIdx.x;
  float rs = 0.f, ks = 0.f;
  for (int i = t; i < NBLK; i += 256) { rs += ws[i]; ks += ws[NBLK + i]; }
#pragma unroll
  for (int off = 32; off; off >>= 1) {
    rs += __shfl_xor(rs, off);
    ks += __shfl_xor(ks, off);
  }
  __shared__ float red[8];
  if ((t & 63) == 0) { red[t >> 6] = rs; red[4 + (t >> 6)] = ks; }
  __syncthreads();
  if (t == 0) {
    float recon = (red[0] + red[1] + red[2] + red[3]) * (1.f / 16777216.f);
    float kl = -0.5f * (red[4] + red[5] + red[6] + red[7]) * (1.f / 262144.f);
    float topo = ws[4096];
    float total = recon + 0.1f * kl + 0.5f * topo;
    out[0] = (float)__float2bfloat16(total);   // high u16 = RNE bf16(total)
    out[1] = (float)__float2bfloat16(recon);
    out[2] = (float)__float2bfloat16(kl);
    out[3] = (float)__float2bfloat16(topo);
  }
}

extern "C" void kernel_launch(void* const* d_in, const int* in_sizes, int n_in,
                              void* d_out, int out_size, void* d_ws, size_t ws_size,
                              hipStream_t stream) {
  const float* rx = (const float*)d_in[0];
  const float* x  = (const float*)d_in[1];
  const float* mu = (const float*)d_in[2];
  const float* lv = (const float*)d_in[3];
  const float* z  = (const float*)d_in[4];

  float* wsf      = (float*)d_ws;
  float* partials = wsf;
  float* topo     = wsf + 4096;
  float* sq       = wsf + 4104;
  float* dist     = wsf + 8192;
  float* out      = (float*)d_out;

  losses_kernel<<<NBLK, 256, 0, stream>>>((const float4*)rx, (const float4*)x,
                                          (const float4*)mu, (const float4*)lv,
                                          z, partials, sq);
  dist_kernel<<<dim3(16, 16), 256, 0, stream>>>(z, sq, dist);
  prim_sil_kernel<<<1, 256, 0, stream>>>(dist, topo);
  final_kernel<<<1, 256, 0, stream>>>(wsf, out);
}

// Round 7
// 338.685 us; speedup vs baseline: 3.7988x; 3.7988x over previous
//
#include <hip/hip_runtime.h>
#include <hip/hip_bf16.h>
#include <math.h>

// ---------------------------------------------------------------------------
// B=1024, D_DATA=16384, D_LAT=256, N_GRID=256. Inputs f32.
// d_out = f32 slots; harness reads high u16 of each slot as bf16, so we store
// (float)__float2bfloat16(v) (proven R6).
//
// MST via Boruvka (10 fixed rounds): all MSTs share the same edge-weight
// multiset, and the silhouette depends only on that multiset. Strict total
// order via key = (w_bits<<32) | (min(i,j)<<10) | max(i,j).
//
// ws layout (floats) — peak usage identical to proven R6 (4.227 MB):
//   [0..1023]     recon partials      [1024..2047] kl partials
//   [2048] topo   [2052] cnt(int)     [2056..3079] sq
//   [3080..4103]  comp (int[1024])    [4104..5126] deaths (1023)
//   [6144..8191]  minedge (u64[1024], byte 24576, 8-aligned)
//   [8192..]      dist 1024x1024 (4 MB)
// ---------------------------------------------------------------------------

#define NBLK 1024

__global__ __launch_bounds__(256) void losses_kernel(const float4* __restrict__ rx,
                                                     const float4* __restrict__ x,
                                                     const float4* __restrict__ mu,
                                                     const float4* __restrict__ lv,
                                                     const float* __restrict__ z,
                                                     float* __restrict__ partials,
                                                     float* __restrict__ sq) {
  const int t = threadIdx.x;
  const int gid = blockIdx.x * 256 + t;
  const int gstride = NBLK * 256;

  float rs = 0.f;
  for (int i = gid; i < 4194304; i += gstride) {
    float4 a = rx[i], b = x[i];
    float dx = a.x - b.x, dy = a.y - b.y, dz = a.z - b.z, dw = a.w - b.w;
    rs += dx * dx + dy * dy + dz * dz + dw * dw;
  }
  float ks = 0.f;
  for (int i = gid; i < 65536; i += gstride) {
    float4 m = mu[i], l = lv[i];
    ks += 1.f + l.x - m.x * m.x - __expf(l.x);
    ks += 1.f + l.y - m.y * m.y - __expf(l.y);
    ks += 1.f + l.z - m.z * m.z - __expf(l.z);
    ks += 1.f + l.w - m.w * m.w - __expf(l.w);
  }
#pragma unroll
  for (int off = 32; off; off >>= 1) {
    rs += __shfl_xor(rs, off);
    ks += __shfl_xor(ks, off);
  }
  __shared__ float red[8];
  if ((t & 63) == 0) { red[t >> 6] = rs; red[4 + (t >> 6)] = ks; }
  __syncthreads();
  if (t == 0) {
    partials[blockIdx.x] = red[0] + red[1] + red[2] + red[3];
    partials[NBLK + blockIdx.x] = red[4] + red[5] + red[6] + red[7];
  }
  if (blockIdx.x < 256) {
    const int lane = t & 63;
    const int row = blockIdx.x * 4 + (t >> 6);
    float4 v = ((const float4*)(z + row * 256))[lane];
    float s = v.x * v.x + v.y * v.y + v.z * v.z + v.w * v.w;
#pragma unroll
    for (int off = 32; off; off >>= 1) s += __shfl_xor(s, off);
    if (lane == 0) sq[row] = s;
  }
}

// dist + fused init of comp/cnt (block (0,0))
__global__ __launch_bounds__(256) void dist_kernel(const float* __restrict__ z,
                                                   const float* __restrict__ sq,
                                                   float* __restrict__ dist,
                                                   int* __restrict__ comp,
                                                   int* __restrict__ cnt) {
  if (blockIdx.x == 0 && blockIdx.y == 0) {
    for (int v = threadIdx.x; v < 1024; v += 256) comp[v] = v;
    if (threadIdx.x == 0) cnt[0] = 0;
  }
  __shared__ float A[64][68];
  __shared__ float Bs[64][68];
  const int i0 = blockIdx.y * 64, j0 = blockIdx.x * 64;
  const int t = threadIdx.x;
  const int tx = t & 15;
  const int ty = t >> 4;
  float acc[4][4] = {};
  for (int k0 = 0; k0 < 256; k0 += 64) {
    __syncthreads();
#pragma unroll
    for (int it = 0; it < 4; ++it) {
      int lin = it * 256 + t;
      int row = lin >> 4, q = lin & 15;
      *(float4*)&A[row][q * 4]  = *(const float4*)(z + (i0 + row) * 256 + k0 + q * 4);
      *(float4*)&Bs[row][q * 4] = *(const float4*)(z + (j0 + row) * 256 + k0 + q * 4);
    }
    __syncthreads();
#pragma unroll 4
    for (int k = 0; k < 64; k += 4) {
      float4 av[4], bv[4];
#pragma unroll
      for (int rr = 0; rr < 4; ++rr) av[rr] = *(const float4*)&A[ty + 16 * rr][k];
#pragma unroll
      for (int cc = 0; cc < 4; ++cc) bv[cc] = *(const float4*)&Bs[tx + 16 * cc][k];
#pragma unroll
      for (int rr = 0; rr < 4; ++rr)
#pragma unroll
        for (int cc = 0; cc < 4; ++cc) {
          acc[rr][cc] += av[rr].x * bv[cc].x;
          acc[rr][cc] += av[rr].y * bv[cc].y;
          acc[rr][cc] += av[rr].z * bv[cc].z;
          acc[rr][cc] += av[rr].w * bv[cc].w;
        }
    }
  }
#pragma unroll
  for (int rr = 0; rr < 4; ++rr) {
    int i = i0 + ty + 16 * rr;
    float sqi = sq[i];
#pragma unroll
    for (int cc = 0; cc < 4; ++cc) {
      int j = j0 + tx + 16 * cc;
      float d2 = sqi + sq[j] - 2.f * acc[rr][cc];
      dist[i * 1024 + j] = sqrtf(fmaxf(d2, 0.f) + 1e-12f);
    }
  }
}

// Boruvka phase A: per-vertex min outgoing edge (1 wave per row, 4 rows/wave-id)
__global__ __launch_bounds__(256) void boruvka_a(const float* __restrict__ dist,
                                                 const int* __restrict__ comp,
                                                 unsigned long long* __restrict__ minedge) {
  const int lane = threadIdx.x & 63;
  const int w = blockIdx.x * 4 + (threadIdx.x >> 6);   // 0..255
#pragma unroll
  for (int rr = 0; rr < 4; ++rr) {
    const int i = w + 256 * rr;
    const int ci = comp[i];
    const float* row = dist + i * 1024;
    unsigned long long best = ~0ull;
    for (int k = 0; k < 16; ++k) {
      int j = lane + 64 * k;
      int cj = comp[j];
      float d = row[j];
      if (cj != ci) {
        int lo = i < j ? i : j, hi = i < j ? j : i;
        unsigned long long key = ((unsigned long long)__float_as_uint(d) << 32)
                               | (unsigned long long)((lo << 10) | hi);
        if (key < best) best = key;
      }
    }
#pragma unroll
    for (int off = 32; off; off >>= 1) {
      unsigned int blolane = __shfl_xor((unsigned int)best, off);
      unsigned int bhilane = __shfl_xor((unsigned int)(best >> 32), off);
      unsigned long long o = ((unsigned long long)bhilane << 32) | blolane;
      if (o < best) best = o;
    }
    if (lane == 0) minedge[i] = best;
  }
}

// Boruvka phase B: component min (LDS atomics), record deaths, union+flatten
__global__ __launch_bounds__(1024) void boruvka_b(const unsigned long long* __restrict__ minedge,
                                                  int* __restrict__ comp,
                                                  float* __restrict__ deaths,
                                                  int* __restrict__ cnt) {
  __shared__ int scomp[1024];
  __shared__ int pnew[1024];
  __shared__ unsigned long long cmin[1024];
  const int t = threadIdx.x;
  scomp[t] = comp[t];
  cmin[t] = ~0ull;
  __syncthreads();
  atomicMin(&cmin[scomp[t]], minedge[t]);
  __syncthreads();
  int parent = scomp[t];
  if (scomp[t] == t) {                       // root
    unsigned long long key = cmin[t];
    if (key != ~0ull) {
      int lo = (int)((key >> 10) & 1023), hi = (int)(key & 1023);
      int clo = scomp[lo], chi = scomp[hi];
      int other = (clo == t) ? chi : clo;
      bool mutual = (cmin[other] == key);
      if (!mutual || t < other) {            // dedupe mutual pair
        int pos = atomicAdd(cnt, 1);
        deaths[pos] = __uint_as_float((unsigned int)(key >> 32));
      }
      parent = (mutual && t < other) ? t : other;
    }
  }
  pnew[t] = parent;
  __syncthreads();
  for (int it = 0; it < 10; ++it) {
    int p = pnew[pnew[t]];
    __syncthreads();
    pnew[t] = p;
    __syncthreads();
  }
  comp[t] = pnew[t];
}

__global__ __launch_bounds__(256) void sil_kernel(const float* __restrict__ deaths,
                                                  float* __restrict__ topo_out) {
  __shared__ float dsh[1023];
  __shared__ float red[8];
  __shared__ float red2[4];
  const int t = threadIdx.x;
  float lmax = 0.f, lsum = 0.f;
  for (int i = t; i < 1023; i += 256) {
    float v = deaths[i];
    dsh[i] = v;
    lmax = fmaxf(lmax, v);
    lsum += v;
  }
#pragma unroll
  for (int off = 32; off; off >>= 1) {
    lmax = fmaxf(lmax, __shfl_xor(lmax, off));
    lsum += __shfl_xor(lsum, off);
  }
  if ((t & 63) == 0) { red[t >> 6] = lmax; red[4 + (t >> 6)] = lsum; }
  __syncthreads();
  float tmax = fmaxf(fmaxf(red[0], red[1]), fmaxf(red[2], red[3]));
  float wsum = red[4] + red[5] + red[6] + red[7];
  float tt = (float)t * (1.0f / 255.0f) * tmax;
  float acc = 0.f;
  for (int j = 0; j < 1023; ++j) {
    float dj = dsh[j];
    acc += dj * fmaxf(fminf(tt, dj - tt), 0.f);
  }
  float phi = acc / (wsum + 1e-12f);
#pragma unroll
  for (int off = 32; off; off >>= 1) phi += __shfl_xor(phi, off);
  if ((t & 63) == 0) red2[t >> 6] = phi;
  __syncthreads();
  if (t == 0) topo_out[0] = (red2[0] + red2[1] + red2[2] + red2[3]) * (1.f / 256.f);
}

__global__ __launch_bounds__(256) void final_kernel(const float* __restrict__ ws,
                                                    float* __restrict__ out) {
  const int t = threadIdx.x;
  float rs = 0.f, ks = 0.f;
  for (int i = t; i < NBLK; i += 256) { rs += ws[i]; ks += ws[NBLK + i]; }
#pragma unroll
  for (int off = 32; off; off >>= 1) {
    rs += __shfl_xor(rs, off);
    ks += __shfl_xor(ks, off);
  }
  __shared__ float red[8];
  if ((t & 63) == 0) { red[t >> 6] = rs; red[4 + (t >> 6)] = ks; }
  __syncthreads();
  if (t == 0) {
    float recon = (red[0] + red[1] + red[2] + red[3]) * (1.f / 16777216.f);
    float kl = -0.5f * (red[4] + red[5] + red[6] + red[7]) * (1.f / 262144.f);
    float topo = ws[2048];
    float total = recon + 0.1f * kl + 0.5f * topo;
    out[0] = (float)__float2bfloat16(total);
    out[1] = (float)__float2bfloat16(recon);
    out[2] = (float)__float2bfloat16(kl);
    out[3] = (float)__float2bfloat16(topo);
  }
}

extern "C" void kernel_launch(void* const* d_in, const int* in_sizes, int n_in,
                              void* d_out, int out_size, void* d_ws, size_t ws_size,
                              hipStream_t stream) {
  const float* rx = (const float*)d_in[0];
  const float* x  = (const float*)d_in[1];
  const float* mu = (const float*)d_in[2];
  const float* lv = (const float*)d_in[3];
  const float* z  = (const float*)d_in[4];

  float* wsf = (float*)d_ws;
  float* partials = wsf;                                   // [0..2047]
  float* topo     = wsf + 2048;
  int*   cnt      = (int*)(wsf + 2052);
  float* sq       = wsf + 2056;
  int*   comp     = (int*)(wsf + 3080);
  float* deaths   = wsf + 4104;
  unsigned long long* minedge = (unsigned long long*)(wsf + 6144);
  float* dist     = wsf + 8192;
  float* out      = (float*)d_out;

  losses_kernel<<<NBLK, 256, 0, stream>>>((const float4*)rx, (const float4*)x,
                                          (const float4*)mu, (const float4*)lv,
                                          z, partials, sq);
  dist_kernel<<<dim3(16, 16), 256, 0, stream>>>(z, sq, dist, comp, cnt);
  for (int r = 0; r < 10; ++r) {
    boruvka_a<<<64, 256, 0, stream>>>(dist, comp, minedge);
    boruvka_b<<<1, 1024, 0, stream>>>(minedge, comp, deaths, cnt);
  }
  sil_kernel<<<1, 256, 0, stream>>>(deaths, topo);
  final_kernel<<<1, 256, 0, stream>>>(wsf, out);
}